// Round 10
// baseline (69.529 us; speedup 1.0000x reference)
//
#include <hip/hip_runtime.h>

namespace {
constexpr int BB = 2;
constexpr int NN = 50000;
constexpr int KK = 16;
constexpr int CI = 64;
constexpr int CO = 32;
constexpr int MM = 4;
constexpr int BN = BB * NN;       // 100000 nodes
constexpr int GROUPS2 = NN / 2;   // 25000 2-node groups per batch
constexpr int GRID = 512;         // 2 blocks/CU (66KB LDS each)
constexpr int WAVES = (GRID / 2) * 4;  // 1024 waves per batch
}

typedef __attribute__((ext_vector_type(8))) short short8v;
typedef __attribute__((ext_vector_type(4))) float float4v;
typedef __attribute__((ext_vector_type(2))) float f32x2;

union F4P {
  float4 f4;
  f32x2 p[2];
};

__device__ __forceinline__ unsigned short bf16r(float f) {
  unsigned int u = __float_as_uint(f);
  u += 0x7FFFu + ((u >> 16) & 1u);
  return (unsigned short)(u >> 16);
}

// async 16B-per-lane global->LDS (lds dst = base + lane*16, wave-uniform base)
__device__ __forceinline__ void llds16(const void* g, void* l) {
  __builtin_amdgcn_global_load_lds(
      (const __attribute__((address_space(1))) unsigned int*)g,
      (__attribute__((address_space(3))) unsigned int*)l, 16, 0, 0);
}

// K1: per node: ux/vx dots + bf16 row xh (one pass over x)
__global__ __launch_bounds__(256) void k_prep(
    const float* __restrict__ x, const float* __restrict__ u,
    const float* __restrict__ v, float* __restrict__ ux,
    float* __restrict__ vx, unsigned short* __restrict__ xh) {
  int idx = blockIdx.x * 256 + threadIdx.x;
  if (idx >= BN) return;
  const float4* xr = (const float4*)(x + (size_t)idx * CI);
  float su[MM] = {0.f, 0.f, 0.f, 0.f};
  float sv[MM] = {0.f, 0.f, 0.f, 0.f};
  uint4 xpack[8];
#pragma unroll
  for (int t = 0; t < CI / 4; ++t) {
    float4 xv = xr[t];
#pragma unroll
    for (int m = 0; m < MM; ++m) {
      float4 uv = *(const float4*)(u + m * CI + t * 4);
      float4 vv = *(const float4*)(v + m * CI + t * 4);
      su[m] += uv.x * xv.x + uv.y * xv.y + uv.z * xv.z + uv.w * xv.w;
      sv[m] += vv.x * xv.x + vv.y * xv.y + vv.z * xv.z + vv.w * xv.w;
    }
    unsigned d0 = (unsigned)bf16r(xv.x) | ((unsigned)bf16r(xv.y) << 16);
    unsigned d1 = (unsigned)bf16r(xv.z) | ((unsigned)bf16r(xv.w) << 16);
    if (t & 1) {
      xpack[t >> 1].z = d0;
      xpack[t >> 1].w = d1;
    } else {
      xpack[t >> 1].x = d0;
      xpack[t >> 1].y = d1;
    }
  }
  ((float4*)ux)[idx] = make_float4(su[0], su[1], su[2], su[3]);
  ((float4*)vx)[idx] = make_float4(sv[0], sv[1], sv[2], sv[3]);
  uint4* xo = (uint4*)(xh + (size_t)idx * CI);
#pragma unroll
  for (int t = 0; t < 8; ++t) xo[t] = xpack[t];
}

// K2: async-staged gather (global_load_lds dbuf) + softmax + packed-FMA
// t-accumulate + MFMA epilogue. 2 nodes (32 edge-rows) per wave-iteration.
__global__ __launch_bounds__(256, 2) void k_gather(
    const unsigned short* __restrict__ xh, const int* __restrict__ adj,
    const float* __restrict__ weight, const float* __restrict__ bias,
    const float* __restrict__ cvec, const float* __restrict__ ux,
    const float* __restrict__ vx, float* __restrict__ out) {
  __shared__ unsigned short w_lds[2 * 8 * 64 * 8];           // 16 KB
  __shared__ unsigned short t_lds[4][8 * 256];               // 16 KB
  __shared__ float q_lds[4][2][64];                          // 2 KB
  __shared__ float inv_lds[4][8];                            // 128 B
  __shared__ __align__(16) char xbuf[4][2][32 * 128];        // 32 KB

  const int tid = threadIdx.x;
  const int lane = tid & 63;
  const int wv = tid >> 6;

  // Stage W as MFMA B-fragments (k = c*4+m ordering, o = tl*16+(l&15))
  for (int i = tid; i < 2 * 8 * 64; i += 256) {
    int tl = i >> 9;
    int ks = (i >> 6) & 7;
    int l = i & 63;
    int o = tl * 16 + (l & 15);
    unsigned pk[4];
#pragma unroll
    for (int ee = 0; ee < 4; ++ee) {
      int k0 = ks * 32 + (l >> 4) * 8 + 2 * ee;
      unsigned lo = bf16r(weight[((k0 & 3) * CO + o) * CI + (k0 >> 2)]);
      unsigned hi =
          bf16r(weight[(((k0 + 1) & 3) * CO + o) * CI + ((k0 + 1) >> 2)]);
      pk[ee] = lo | (hi << 16);
    }
    *(uint4*)&w_lds[i * 8] = make_uint4(pk[0], pk[1], pk[2], pk[3]);
  }
  __syncthreads();

  const int m4 = lane & 3;
  const int k4 = lane >> 2;
  const float cm = cvec[m4];
  const float b0 = bias[lane & 15];
  const float b1 = bias[16 + (lane & 15)];

  // XCD partition: XCDs 0-3 -> batch 0, 4-7 -> batch 1
  const int xcd = blockIdx.x & 7;
  const int b = xcd >> 2;
  const int wb = ((blockIdx.x >> 3) << 2) | (xcd & 3);
  const int w = wb * 4 + wv;
  const size_t bbase = (size_t)b * NN;
  const unsigned short* xhb = xh + bbase * CI;
  const float* vxb = vx + bbase * MM;
  unsigned short* twv = t_lds[wv];
  char* xwv = &xbuf[wv][0][0];

// issue 4 async gll covering 32 edge-rows of group (2 nodes) into buf B
#define STAGE(B, AV)                                                       \
  {                                                                        \
    char* ldst = xwv + (B)*4096;                                           \
    _Pragma("unroll") for (int li = 0; li < 4; ++li) {                     \
      int e = li * 8 + (lane >> 3);                                        \
      int rr = __shfl((AV), e);                                            \
      unsigned r = (unsigned)(max(rr, 1) - 1);                             \
      const char* ga = (const char*)xhb + (size_t)r * 128 + (lane & 7) * 16;\
      llds16(ga, ldst + li * 1024);                                        \
    }                                                                      \
  }

// 16 MFMAs over 8 staged t-rows; store valid rows (row<2*JR)
#define FLUSH(JR)                                                          \
  {                                                                        \
    float4v ac0 = {0.f, 0.f, 0.f, 0.f};                                    \
    float4v ac1 = {0.f, 0.f, 0.f, 0.f};                                    \
    const int arow = lane & 7;                                             \
    const unsigned axor = (unsigned)(arow & 7) << 4;                       \
    _Pragma("unroll") for (int ks = 0; ks < 8; ++ks) {                     \
      unsigned aoff =                                                      \
          (unsigned)arow * 512u +                                          \
          ((((unsigned)(lane >> 4)) * 16u + (unsigned)ks * 64u) ^ axor);   \
      short8v A = *(const short8v*)((const char*)twv + aoff);              \
      short8v Bl = *(const short8v*)&w_lds[(0 * 8 + ks) * 512 + lane * 8]; \
      short8v Bh = *(const short8v*)&w_lds[(1 * 8 + ks) * 512 + lane * 8]; \
      ac0 = __builtin_amdgcn_mfma_f32_16x16x32_bf16(A, Bl, ac0, 0, 0, 0);  \
      ac1 = __builtin_amdgcn_mfma_f32_16x16x32_bf16(A, Bh, ac1, 0, 0, 0);  \
    }                                                                      \
    const int jj = lane >> 4;                                              \
    _Pragma("unroll") for (int ri = 0; ri < 4; ++ri) {                     \
      int r = jj * 4 + ri;                                                 \
      int gr = gbase + (r >> 1) * WAVES;                                   \
      if (r < 2 * (JR) && gr < GROUPS2) {                                  \
        float iv = inv_lds[wv][r];                                         \
        size_t bn = bbase + (size_t)gr * 2 + (r & 1);                      \
        out[bn * CO + (lane & 15)] = ac0[ri] * iv + b0;                    \
        out[bn * CO + 16 + (lane & 15)] = ac1[ri] * iv + b1;               \
      }                                                                    \
    }                                                                      \
  }

  int g = w;
  int av = 0;
  if (g < GROUPS2) av = adj[(bbase + (size_t)g * 2) * KK + (lane & 31)];
  if (g < GROUPS2) STAGE(0, av)  // prologue: current tile in flight
  int gn = g + WAVES;
  int av_n = 0;
  if (gn < GROUPS2) av_n = adj[(bbase + (size_t)gn * 2) * KK + (lane & 31)];

  int cur = 0;
  int jrows = 0;
  int gbase = g;

  while (g < GROUPS2) {
    const int av_c = av;
    const size_t bn0 = bbase + (size_t)g * 2;

    // oldest loads first: softmax-side gathers for this group
    int as0 = __shfl(av_c, k4);
    int as1 = __shfl(av_c, 16 + k4);
    float vg0 = vxb[(size_t)(max(as0, 1) - 1) * MM + m4];
    float vg1 = vxb[(size_t)(max(as1, 1) - 1) * MM + m4];
    float ux0 = ux[bn0 * MM + m4];
    float ux1 = ux[(bn0 + 1) * MM + m4];

    // adjacency prefetch two tiles ahead
    const int gnn = gn + WAVES;
    int av_nn = 0;
    if (gnn < GROUPS2)
      av_nn = adj[(bbase + (size_t)gnn * 2) * KK + (lane & 31)];

    // async-stage NEXT tile into the other buffer (stays in flight)
    const bool staged = (gn < GROUPS2);
    if (staged) STAGE(cur ^ 1, av_n)

    // softmax for 2 nodes, deg-norm NOT folded (applied in FLUSH)
    const unsigned long long msk = __ballot(av_c != 0);
    {
      int d0 = __popc((unsigned)(msk & 0xFFFFull));
      int d1 = __popc((unsigned)((msk >> 16) & 0xFFFFull));
      float i0 = d0 ? __builtin_amdgcn_rcpf((float)d0) : 0.f;
      float i1 = d1 ? __builtin_amdgcn_rcpf((float)d1) : 0.f;
      float e0 = __expf(vg0 + ux0 + cm);
      float e1 = __expf(vg1 + ux1 + cm);
      float s0 = e0 + __shfl_xor(e0, 1);
      float s1 = e1 + __shfl_xor(e1, 1);
      s0 += __shfl_xor(s0, 2);
      s1 += __shfl_xor(s1, 2);
      q_lds[wv][0][lane] = (as0 != 0) ? e0 * __builtin_amdgcn_rcpf(s0) : 0.f;
      q_lds[wv][1][lane] = (as1 != 0) ? e1 * __builtin_amdgcn_rcpf(s1) : 0.f;
      if (lane == 0)
        *(float2*)&inv_lds[wv][jrows * 2] = make_float2(i0, i1);
    }

    // wait for CURRENT tile only: newest 5 (av_nn + 4 gll) may stay in flight
    if (staged)
      asm volatile("s_waitcnt vmcnt(5)" ::: "memory");
    else
      asm volatile("s_waitcnt vmcnt(0)" ::: "memory");

    // t-accumulate from LDS: half-wave per node, 2 channels per lane
    {
      const char* xb = xwv + cur * 4096;
      const int hn = lane >> 5;
      const int c2 = lane & 31;
      const float4* qp = (const float4*)&q_lds[wv][hn][0];
      f32x2 a0 = {0.f, 0.f}, a1 = {0.f, 0.f};
      f32x2 a2 = {0.f, 0.f}, a3 = {0.f, 0.f};
#pragma unroll
      for (int k = 0; k < KK; ++k) {
        unsigned xx = *(const unsigned*)(xb + hn * 2048 + k * 128 + c2 * 4);
        float xlo = __uint_as_float(xx << 16);
        float xhi = __uint_as_float(xx & 0xFFFF0000u);
        F4P q;
        q.f4 = qp[k];
        a0 += q.p[0] * xlo;
        a1 += q.p[1] * xlo;
        a2 += q.p[0] * xhi;
        a3 += q.p[1] * xhi;
      }
      unsigned p0, p1, p2, p3;
      asm("v_cvt_pk_bf16_f32 %0, %1, %2" : "=v"(p0) : "v"(a0[0]), "v"(a0[1]));
      asm("v_cvt_pk_bf16_f32 %0, %1, %2" : "=v"(p1) : "v"(a1[0]), "v"(a1[1]));
      asm("v_cvt_pk_bf16_f32 %0, %1, %2" : "=v"(p2) : "v"(a2[0]), "v"(a2[1]));
      asm("v_cvt_pk_bf16_f32 %0, %1, %2" : "=v"(p3) : "v"(a3[0]), "v"(a3[1]));
      int row = jrows * 2 + hn;
      unsigned boff = (unsigned)row * 512u +
                      (((unsigned)c2 * 16u) ^ ((unsigned)(row & 7) << 4));
      *(uint4*)((char*)twv + boff) = make_uint4(p0, p1, p2, p3);
    }

    av = av_n;
    av_n = av_nn;
    g = gn;
    gn = gnn;
    cur ^= 1;
    ++jrows;
    if (jrows == 4) {
      FLUSH(4)
      jrows = 0;
      gbase = g;
    }
  }
  if (jrows > 0) FLUSH(jrows)
}

// ---------- fallback path (ws too small): all-fp32 ----------
__global__ __launch_bounds__(256) void k_uxvx(
    const float* __restrict__ x, const float* __restrict__ u,
    const float* __restrict__ v, float* __restrict__ ux,
    float* __restrict__ vx) {
  int idx = blockIdx.x * 256 + threadIdx.x;
  if (idx >= BN) return;
  const float4* xr = (const float4*)(x + (size_t)idx * CI);
  float su[MM] = {0.f, 0.f, 0.f, 0.f};
  float sv[MM] = {0.f, 0.f, 0.f, 0.f};
#pragma unroll
  for (int t = 0; t < CI / 4; ++t) {
    float4 xv = xr[t];
#pragma unroll
    for (int m = 0; m < MM; ++m) {
      float4 uv = *(const float4*)(u + m * CI + t * 4);
      float4 vv = *(const float4*)(v + m * CI + t * 4);
      su[m] += uv.x * xv.x + uv.y * xv.y + uv.z * xv.z + uv.w * xv.w;
      sv[m] += vv.x * xv.x + vv.y * xv.y + vv.z * xv.z + vv.w * xv.w;
    }
  }
  ((float4*)ux)[idx] = make_float4(su[0], su[1], su[2], su[3]);
  ((float4*)vx)[idx] = make_float4(sv[0], sv[1], sv[2], sv[3]);
}

__global__ __launch_bounds__(256) void k_main_old(
    const float* __restrict__ x, const int* __restrict__ adj,
    const float* __restrict__ weight, const float* __restrict__ bias,
    const float* __restrict__ cvec, const float* __restrict__ ux,
    const float* __restrict__ vx, float* __restrict__ out) {
  __shared__ float w_lds2[MM][CO][CI + 4];
  __shared__ float q_lds2[4][64];
  __shared__ float t_lds2[4][MM][CI];
  const int tid = threadIdx.x;
  const int lane = tid & 63;
  const int wv = tid >> 6;
#pragma unroll
  for (int i = 0; i < (MM * CO * CI) / 256; ++i) {
    int g = i * 256 + tid;
    w_lds2[g >> 11][(g >> 6) & (CO - 1)][g & (CI - 1)] = weight[g];
  }
  __syncthreads();
  const int k4 = lane >> 2;
  const int m4 = lane & 3;
  const int o = lane & 31;
  const int hh = lane >> 5;
  const float cm = cvec[m4];
  const float bo = bias[o];
  for (int g = blockIdx.x; g < BN / 4; g += gridDim.x) {
    const int bn = g * 4 + wv;
    const int b = (bn >= NN) ? 1 : 0;
    const int* adjp = adj + (size_t)bn * KK;
    const float* xb = x + (size_t)b * NN * CI;
    int4 A[4];
#pragma unroll
    for (int i = 0; i < 4; ++i) A[i] = ((const int4*)adjp)[i];
    int deg = 0;
#pragma unroll
    for (int i = 0; i < 4; ++i)
      deg += (A[i].x != 0) + (A[i].y != 0) + (A[i].z != 0) + (A[i].w != 0);
    const float inv_deg = (deg > 0) ? 1.0f / (float)deg : 0.0f;
    int a = adjp[k4];
    float vg = 0.f;
    if (a != 0) vg = vx[((size_t)b * NN + (a - 1)) * MM + m4];
    float logit = vg + ux[(size_t)bn * MM + m4] + cm;
    float mx = fmaxf(logit, __shfl_xor(logit, 1));
    mx = fmaxf(mx, __shfl_xor(mx, 2));
    float e = __expf(logit - mx);
    float s = e + __shfl_xor(e, 1);
    s += __shfl_xor(s, 2);
    q_lds2[wv][lane] = (a != 0) ? (e / s) : 0.f;
    int rows[KK];
    {
      int tmp[KK] = {A[0].x, A[0].y, A[0].z, A[0].w, A[1].x, A[1].y,
                     A[1].z, A[1].w, A[2].x, A[2].y, A[2].z, A[2].w,
                     A[3].x, A[3].y, A[3].z, A[3].w};
#pragma unroll
      for (int k = 0; k < KK; ++k) rows[k] = max(tmp[k], 1) - 1;
    }
    float xg[KK];
#pragma unroll
    for (int k = 0; k < KK; ++k) xg[k] = xb[(size_t)rows[k] * CI + lane];
    float t0 = 0.f, t1 = 0.f, t2 = 0.f, t3 = 0.f;
#pragma unroll
    for (int k = 0; k < KK; ++k) {
      float4 qv = *(const float4*)&q_lds2[wv][k * 4];
      t0 += qv.x * xg[k];
      t1 += qv.y * xg[k];
      t2 += qv.z * xg[k];
      t3 += qv.w * xg[k];
    }
    t_lds2[wv][0][lane] = t0;
    t_lds2[wv][1][lane] = t1;
    t_lds2[wv][2][lane] = t2;
    t_lds2[wv][3][lane] = t3;
    float a0 = 0.f, a1 = 0.f, a2 = 0.f, a3 = 0.f;
#pragma unroll
    for (int mm = 0; mm < 2; ++mm) {
      const float* wrow = &w_lds2[2 * hh + mm][o][0];
      const float* trow = &t_lds2[wv][2 * hh + mm][0];
#pragma unroll
      for (int t4 = 0; t4 < CI / 4; ++t4) {
        float4 wvv = *(const float4*)(wrow + 4 * t4);
        float4 tv = *(const float4*)(trow + 4 * t4);
        a0 += wvv.x * tv.x;
        a1 += wvv.y * tv.y;
        a2 += wvv.z * tv.z;
        a3 += wvv.w * tv.w;
      }
    }
    float acc = (a0 + a1) + (a2 + a3);
    acc += __shfl_xor(acc, 32);
    if (lane < 32) out[(size_t)bn * CO + o] = acc * inv_deg + bo;
  }
}

extern "C" void kernel_launch(void* const* d_in, const int* in_sizes, int n_in,
                              void* d_out, int out_size, void* d_ws,
                              size_t ws_size, hipStream_t stream) {
  const float* x = (const float*)d_in[0];
  const int* adj = (const int*)d_in[1];
  const float* weight = (const float*)d_in[2];
  const float* bias = (const float*)d_in[3];
  const float* u = (const float*)d_in[4];
  const float* v = (const float*)d_in[5];
  const float* cvec = (const float*)d_in[6];
  float* out = (float*)d_out;

  float* ux = (float*)d_ws;          // BN*4 f32
  float* vx = ux + (size_t)BN * MM;  // BN*4 f32
  const size_t base = (size_t)BN * MM * 2 * sizeof(float);           // 3.2 MB
  const size_t xh_bytes = (size_t)BN * CI * sizeof(unsigned short);  // 12.8 MB

  if (ws_size >= base + xh_bytes) {
    unsigned short* xhb = (unsigned short*)((char*)d_ws + base);
    k_prep<<<(BN + 255) / 256, 256, 0, stream>>>(x, u, v, ux, vx, xhb);
    k_gather<<<GRID, 256, 0, stream>>>(xhb, adj, weight, bias, cvec, ux, vx,
                                       out);
  } else {
    k_uxvx<<<(BN + 255) / 256, 256, 0, stream>>>(x, u, v, ux, vx);
    k_main_old<<<1024, 256, 0, stream>>>(x, adj, weight, bias, cvec, ux, vx,
                                         out);
  }
}